// Round 4
// baseline (67.505 us; speedup 1.0000x reference)
//
#include <hip/hip_runtime.h>
#include <hip/hip_bf16.h>

typedef __attribute__((ext_vector_type(4))) float  f4;
typedef __attribute__((ext_vector_type(8))) short  short8;
typedef __attribute__((ext_vector_type(4))) float  f32x4;

static constexpr int NHEAD = 16;
static constexpr int NIN   = 128;
static constexpr int NOUT  = 128;
static constexpr int NROWS = 8 * 2048;          // B*S = 16384
static constexpr int RSTR  = NHEAD * NIN;       // 2048 floats per (b,s) row
static constexpr int TILES = 4;                 // 16-row tiles per wave
static constexpr int ROWS_PER_BLOCK = 128 * TILES;        // 8 waves x 16 rows x 4
static constexpr int BLOCKS_X = NROWS / ROWS_PER_BLOCK;   // 32

static __device__ inline unsigned short f2bfu(float f) {
  union { __hip_bfloat16 h; unsigned short u; } v;
  v.h = __float2bfloat16(f);
  return v.u;
}

static __device__ inline short8 cvt8(f4 a, f4 b) {
  short8 r;
  r[0] = (short)f2bfu(a[0]); r[1] = (short)f2bfu(a[1]);
  r[2] = (short)f2bfu(a[2]); r[3] = (short)f2bfu(a[3]);
  r[4] = (short)f2bfu(b[0]); r[5] = (short)f2bfu(b[1]);
  r[6] = (short)f2bfu(b[2]); r[7] = (short)f2bfu(b[3]);
  return r;
}

__global__ __launch_bounds__(512, 4)
void bdp_kernel(const float* __restrict__ X, const float* __restrict__ W,
                float* __restrict__ O) {
  // W(head) as bf16 MFMA A-fragments, fragment-contiguous (zero bank conflict):
  // frag = n*4 + kk; lane holds o = n*16 + (lane&15), k = kk*32 + (lane>>4)*8 + j.
  __shared__ short8 wtile[32][64];

  const int head = blockIdx.y;
  const int tid  = (int)threadIdx.x;
  const int lane = tid & 63;
  const int wid  = tid >> 6;      // 8 waves
  const int lr   = lane & 15;
  const int lq   = lane >> 4;

  const int rowbase = (int)blockIdx.x * ROWS_PER_BLOCK + wid * 16;
  const float* xr = X + (size_t)(rowbase + lr) * RSTR + head * NIN;

  // ---- depth-2 prefetch: issue tiles 0 and 1 before W staging ----
  f4 xs[2][8];                    // [slot][2*kk + half], 32 VGPR each
  #pragma unroll
  for (int kk = 0; kk < 4; ++kk) {
    const int koff = kk * 32 + lq * 8;
    xs[0][2*kk]   = *reinterpret_cast<const f4*>(xr + koff);
    xs[0][2*kk+1] = *reinterpret_cast<const f4*>(xr + koff + 4);
  }
  {
    const float* xr1 = xr + (size_t)128 * RSTR;
    #pragma unroll
    for (int kk = 0; kk < 4; ++kk) {
      const int koff = kk * 32 + lq * 8;
      xs[1][2*kk]   = *reinterpret_cast<const f4*>(xr1 + koff);
      xs[1][2*kk+1] = *reinterpret_cast<const f4*>(xr1 + koff + 4);
    }
  }

  // ---- stage W(head): each wave writes 4 of the 32 fragments ----
  const float* Wh = W + (size_t)head * NOUT * NIN;
  #pragma unroll
  for (int it = 0; it < 4; ++it) {
    const int frag = wid * 4 + it;
    const int n  = frag >> 2;
    const int kk = frag & 3;
    const float* src = Wh + (n * 16 + lr) * NIN + kk * 32 + lq * 8;
    f4 a = *reinterpret_cast<const f4*>(src);
    f4 b = *reinterpret_cast<const f4*>(src + 4);
    wtile[frag][lane] = cvt8(a, b);
  }
  __syncthreads();

  // ---- 4 tiles, barrier-free; prefetch t+2 while computing t ----
  #pragma unroll
  for (int t = 0; t < TILES; ++t) {
    const int slot = t & 1;

    // convert tile t (waits only on slot's loads; other slot stays in flight)
    short8 xv[4];
    #pragma unroll
    for (int kk = 0; kk < 4; ++kk)
      xv[kk] = cvt8(xs[slot][2*kk], xs[slot][2*kk+1]);

    // reissue this slot for tile t+2 — flies under the MFMAs + stores below
    if (t + 2 < TILES) {
      const float* xrn = xr + (size_t)(t + 2) * 128 * RSTR;
      #pragma unroll
      for (int kk = 0; kk < 4; ++kk) {
        const int koff = kk * 32 + lq * 8;
        xs[slot][2*kk]   = *reinterpret_cast<const f4*>(xrn + koff);
        xs[slot][2*kk+1] = *reinterpret_cast<const f4*>(xrn + koff + 4);
      }
    }

    f32x4 acc[8];
    #pragma unroll
    for (int n = 0; n < 8; ++n) acc[n] = (f32x4){0.f, 0.f, 0.f, 0.f};

    #pragma unroll
    for (int kk = 0; kk < 4; ++kk) {
      #pragma unroll
      for (int n = 0; n < 8; ++n) {
        // A = W frag (rows = o), B = X frag (cols = x-row)
        acc[n] = __builtin_amdgcn_mfma_f32_16x16x32_bf16(
            wtile[n * 4 + kk][lane], xv[kk], acc[n], 0, 0, 0);
      }
    }

    // D[o][xrow]: lane holds xrow = lane&15, o = n*16 + lq*4 + reg.
    // 4 consecutive o per lane -> dwordx4 stores (normal, L2 write-combined).
    float* dst = O + (size_t)(rowbase + t * 128 + lr) * RSTR + head * NOUT;
    #pragma unroll
    for (int n = 0; n < 8; ++n) {
      *reinterpret_cast<f4*>(dst + n * 16 + lq * 4) = acc[n];
    }
  }
}

extern "C" void kernel_launch(void* const* d_in, const int* in_sizes, int n_in,
                              void* d_out, int out_size, void* d_ws, size_t ws_size,
                              hipStream_t stream) {
  const float* X = (const float*)d_in[0];   // [8,2048,16,128] f32
  const float* W = (const float*)d_in[1];   // [16,128,128] f32
  float* O = (float*)d_out;                 // [8,2048,16,128] f32
  dim3 grid(BLOCKS_X, NHEAD);
  bdp_kernel<<<grid, dim3(512), 0, stream>>>(X, W, O);
}

// Round 6
// 52.265 us; speedup vs baseline: 1.2916x; 1.2916x over previous
//
#include <hip/hip_runtime.h>
#include <hip/hip_bf16.h>

typedef __attribute__((ext_vector_type(4))) float  f4;
typedef __attribute__((ext_vector_type(8))) short  short8;
typedef __attribute__((ext_vector_type(4))) float  f32x4;

static constexpr int NHEAD = 16;
static constexpr int NIN   = 128;
static constexpr int NOUT  = 128;
static constexpr int NROWS = 8 * 2048;          // B*S = 16384
static constexpr int RSTR  = NHEAD * NIN;       // 2048 floats per (b,s) row
static constexpr int TILES = 4;                 // 16-row tiles per wave
static constexpr int ROWS_PER_BLOCK = 128 * TILES;        // 512
static constexpr int BLOCKS_X = NROWS / ROWS_PER_BLOCK;   // 32  (grid 32x16=512 WGs)

static __device__ inline unsigned short f2bfu(float f) {
  union { __hip_bfloat16 h; unsigned short u; } v;
  v.h = __float2bfloat16(f);
  return v.u;
}

static __device__ inline short8 cvt8(f4 a, f4 b) {
  short8 r;
  r[0] = (short)f2bfu(a[0]); r[1] = (short)f2bfu(a[1]);
  r[2] = (short)f2bfu(a[2]); r[3] = (short)f2bfu(a[3]);
  r[4] = (short)f2bfu(b[0]); r[5] = (short)f2bfu(b[1]);
  r[6] = (short)f2bfu(b[2]); r[7] = (short)f2bfu(b[3]);
  return r;
}

__global__ __launch_bounds__(512, 4)   // cap VGPR at 128 -> 2 WGs/CU (16 waves)
void bdp_kernel(const float* __restrict__ X, const float* __restrict__ W,
                float* __restrict__ O) {
  // W(head) as bf16 MFMA A-fragments, fragment-contiguous (0 bank conflicts):
  // frag = n*4 + kk; lane holds o = n*16 + (lane&15), k = kk*32 + (lane>>4)*8 + j.
  __shared__ short8 wtile[32][64];

  const int head = blockIdx.y;
  const int tid  = (int)threadIdx.x;
  const int lane = tid & 63;
  const int wid  = tid >> 6;      // 8 waves
  const int lr   = lane & 15;
  const int lq   = lane >> 4;

  const int rowbase = (int)blockIdx.x * ROWS_PER_BLOCK + wid * 16;
  const float* xr = X + (size_t)(rowbase + lr) * RSTR + head * NIN;

  // ---- depth-2 prefetch: tiles 0 and 1 issued before W staging; PINNED ----
  f4 xs0[8], xs1[8];              // two named slots (static indexing, rule #20)
  #pragma unroll
  for (int kk = 0; kk < 4; ++kk) {
    const int koff = kk * 32 + lq * 8;
    xs0[2*kk]   = *reinterpret_cast<const f4*>(xr + koff);
    xs0[2*kk+1] = *reinterpret_cast<const f4*>(xr + koff + 4);
  }
  {
    const float* xr1 = xr + (size_t)128 * RSTR;
    #pragma unroll
    for (int kk = 0; kk < 4; ++kk) {
      const int koff = kk * 32 + lq * 8;
      xs1[2*kk]   = *reinterpret_cast<const f4*>(xr1 + koff);
      xs1[2*kk+1] = *reinterpret_cast<const f4*>(xr1 + koff + 4);
    }
  }
  __builtin_amdgcn_sched_barrier(0);   // loads may NOT sink past this point

  // ---- stage W(head): each wave writes 4 of the 32 fragments ----
  const float* Wh = W + (size_t)head * NOUT * NIN;
  #pragma unroll
  for (int it = 0; it < 4; ++it) {
    const int frag = wid * 4 + it;
    const int n  = frag >> 2;
    const int kk = frag & 3;
    const float* src = Wh + (n * 16 + lr) * NIN + kk * 32 + lq * 8;
    f4 a = *reinterpret_cast<const f4*>(src);
    f4 b = *reinterpret_cast<const f4*>(src + 4);
    wtile[frag][lane] = cvt8(a, b);
  }
  __syncthreads();

  // Tile body: per-kk cvt (single live xv) -> 8 MFMA; then pinned prefetch
  // of tile t+2 into the freed slot; then stores (more cover for the loads).
#define TILE_BODY(xsC, T, PF)                                              \
  {                                                                        \
    f32x4 acc[8];                                                          \
    _Pragma("unroll")                                                      \
    for (int n = 0; n < 8; ++n) acc[n] = (f32x4){0.f, 0.f, 0.f, 0.f};      \
    _Pragma("unroll")                                                      \
    for (int kk = 0; kk < 4; ++kk) {                                       \
      short8 xv = cvt8(xsC[2*kk], xsC[2*kk+1]);                            \
      _Pragma("unroll")                                                    \
      for (int n = 0; n < 8; ++n)                                          \
        acc[n] = __builtin_amdgcn_mfma_f32_16x16x32_bf16(                  \
            wtile[n*4+kk][lane], xv, acc[n], 0, 0, 0);                     \
    }                                                                      \
    if (PF) {                                                              \
      const float* xrn = xr + (size_t)((T) + 2) * 128 * RSTR;              \
      _Pragma("unroll")                                                    \
      for (int kk = 0; kk < 4; ++kk) {                                     \
        const int koff = kk * 32 + lq * 8;                                 \
        xsC[2*kk]   = *reinterpret_cast<const f4*>(xrn + koff);            \
        xsC[2*kk+1] = *reinterpret_cast<const f4*>(xrn + koff + 4);        \
      }                                                                    \
      __builtin_amdgcn_sched_barrier(0);                                   \
    }                                                                      \
    float* dst = O + (size_t)(rowbase + (T) * 128 + lr) * RSTR + head*NOUT;\
    _Pragma("unroll")                                                      \
    for (int n = 0; n < 8; ++n)                                            \
      *reinterpret_cast<f4*>(dst + n * 16 + lq * 4) = acc[n];              \
  }

  TILE_BODY(xs0, 0, 1)
  TILE_BODY(xs1, 1, 1)
  TILE_BODY(xs0, 2, 0)
  TILE_BODY(xs1, 3, 0)
#undef TILE_BODY
}

extern "C" void kernel_launch(void* const* d_in, const int* in_sizes, int n_in,
                              void* d_out, int out_size, void* d_ws, size_t ws_size,
                              hipStream_t stream) {
  const float* X = (const float*)d_in[0];   // [8,2048,16,128] f32
  const float* W = (const float*)d_in[1];   // [16,128,128] f32
  float* O = (float*)d_out;                 // [8,2048,16,128] f32
  dim3 grid(BLOCKS_X, NHEAD);
  bdp_kernel<<<grid, dim3(512), 0, stream>>>(X, W, O);
}